// Round 8
// baseline (3163.944 us; speedup 1.0000x reference)
//
#include <hip/hip_runtime.h>

// ==== model dims (fixed by the reference) ====
constexpr int B_  = 2, S_ = 1024, T_ = 2048;   // T = B*S tokens
constexpr int D_  = 512, H_ = 8, DH_ = 64;
constexpr int L_  = 12, E_ = 8, FF_ = 2048;
constexpr int V_  = 32000, D3_ = 1536;

using half8_t = __attribute__((ext_vector_type(8))) _Float16;
using half2_t = __attribute__((ext_vector_type(2))) _Float16;
using f32x4_t = __attribute__((ext_vector_type(4))) float;

// ---------- helpers ----------
__device__ __forceinline__ float wred(float v){
#pragma unroll
  for (int off = 32; off; off >>= 1) v += __shfl_xor(v, off);
  return v;
}
__device__ __forceinline__ float gelu_f(float v){
  return 0.5f * v * (1.f + erff(v * 0.70710678118654752f));
}

// ---------- embedding ----------
__global__ void k_embed(const int* __restrict__ ids, const float* __restrict__ tok,
                        const float* __restrict__ pos, float* __restrict__ x){
  int t = blockIdx.x;
  int s = t & (S_ - 1);
  int id = ids[t];
  const float* tr = tok + (size_t)id * D_;
  const float* pr = pos + (size_t)s  * D_;
  float* xr = x + (size_t)t * D_;
  for (int d = threadIdx.x; d < D_; d += blockDim.x) xr[d] = tr[d] + pr[d];
}

// ---------- fused rmsnorm#2 + router: one wave per token ----------
__global__ __launch_bounds__(64) void k_norm_router(
    const float* __restrict__ x, const float* __restrict__ nw,
    const float* __restrict__ rW, const float* __restrict__ rb,
    float* __restrict__ h, float* __restrict__ rl_out,
    float* __restrict__ topw, int* __restrict__ topi){
  const int t = blockIdx.x, lane = threadIdx.x;
  const float* xr = x + (size_t)t * D_;
  const float4 xv0 = *reinterpret_cast<const float4*>(xr + (lane << 2));
  const float4 xv1 = *reinterpret_cast<const float4*>(xr + 256 + (lane << 2));
  float ss = xv0.x*xv0.x + xv0.y*xv0.y + xv0.z*xv0.z + xv0.w*xv0.w
           + xv1.x*xv1.x + xv1.y*xv1.y + xv1.z*xv1.z + xv1.w*xv1.w;
  ss = wred(ss);
  const float sc = rsqrtf(ss * (1.f / (float)D_) + 1e-6f);
  const float4 w0 = *reinterpret_cast<const float4*>(nw + (lane << 2));
  const float4 w1 = *reinterpret_cast<const float4*>(nw + 256 + (lane << 2));
  float hv[8];
  hv[0] = xv0.x*sc*w0.x; hv[1] = xv0.y*sc*w0.y; hv[2] = xv0.z*sc*w0.z; hv[3] = xv0.w*sc*w0.w;
  hv[4] = xv1.x*sc*w1.x; hv[5] = xv1.y*sc*w1.y; hv[6] = xv1.z*sc*w1.z; hv[7] = xv1.w*sc*w1.w;
  float* hr = h + (size_t)t * D_;
  *reinterpret_cast<float4*>(hr + (lane << 2))       = make_float4(hv[0], hv[1], hv[2], hv[3]);
  *reinterpret_cast<float4*>(hr + 256 + (lane << 2)) = make_float4(hv[4], hv[5], hv[6], hv[7]);
  float acc[8] = {0,0,0,0,0,0,0,0};
#pragma unroll
  for (int u = 0; u < 8; u++){
    const int d = (u < 4) ? ((lane << 2) + u) : (256 + (lane << 2) + u - 4);
    const float4 ra = *reinterpret_cast<const float4*>(rW + (size_t)d * E_);
    const float4 rb4 = *reinterpret_cast<const float4*>(rW + (size_t)d * E_ + 4);
    acc[0] += hv[u]*ra.x;  acc[1] += hv[u]*ra.y;  acc[2] += hv[u]*ra.z;  acc[3] += hv[u]*ra.w;
    acc[4] += hv[u]*rb4.x; acc[5] += hv[u]*rb4.y; acc[6] += hv[u]*rb4.z; acc[7] += hv[u]*rb4.w;
  }
  float rl[8];
#pragma unroll
  for (int e = 0; e < 8; e++) rl[e] = wred(acc[e]) + rb[e];
  float mx = rl[0];
#pragma unroll
  for (int e = 1; e < 8; e++) mx = fmaxf(mx, rl[e]);
  float p[8], s = 0.f;
#pragma unroll
  for (int e = 0; e < 8; e++){ p[e] = __expf(rl[e] - mx); s += p[e]; }
  const float inv = 1.f / s;
  int arg = 0; float best = rl[0];
#pragma unroll
  for (int e = 1; e < 8; e++) if (rl[e] > best){ best = rl[e]; arg = e; }
  if (lane == 0){
#pragma unroll
    for (int e = 0; e < 8; e++) rl_out[(size_t)t * E_ + e] = rl[e];
    topw[t] = p[arg] * inv;
    topi[t] = arg;
  }
}

// ---------- parallel routing scan: one 1024-thread block ----------
__global__ __launch_bounds__(1024) void k_route_scan2(
    const int* __restrict__ topi, const float* __restrict__ rl,
    int* __restrict__ seg, int* __restrict__ perm, float* __restrict__ aux){
  __shared__ int cnt[8], segs[9], cur[8];
  __shared__ float psums[8];
  const int tid = threadIdx.x;
  if (tid < 8){ cnt[tid] = 0; psums[tid] = 0.f; }
  __syncthreads();
  const int t0 = tid, t1 = tid + 1024;
  const int e0 = topi[t0], e1 = topi[t1];
  atomicAdd(&cnt[e0], 1);
  atomicAdd(&cnt[e1], 1);
  float ps[8] = {0,0,0,0,0,0,0,0};
#pragma unroll
  for (int k = 0; k < 2; k++){
    const float* r = rl + (size_t)(k ? t1 : t0) * E_;
    float v[8];
#pragma unroll
    for (int e = 0; e < 8; e++) v[e] = r[e];
    float mx = v[0];
#pragma unroll
    for (int e = 1; e < 8; e++) mx = fmaxf(mx, v[e]);
    float s = 0.f;
#pragma unroll
    for (int e = 0; e < 8; e++){ v[e] = __expf(v[e] - mx); s += v[e]; }
    const float is = 1.f / s;
#pragma unroll
    for (int e = 0; e < 8; e++) ps[e] += v[e] * is;
  }
#pragma unroll
  for (int e = 0; e < 8; e++) ps[e] = wred(ps[e]);
  if ((tid & 63) == 0){
#pragma unroll
    for (int e = 0; e < 8; e++) atomicAdd(&psums[e], ps[e]);
  }
  __syncthreads();
  if (tid == 0){
    segs[0] = 0;
#pragma unroll
    for (int e = 0; e < 8; e++) segs[e + 1] = segs[e] + cnt[e];
#pragma unroll
    for (int e = 0; e < 8; e++) cur[e] = segs[e];
  }
  __syncthreads();
  if (tid < 9) seg[tid] = segs[tid];
  const int p0 = atomicAdd(&cur[e0], 1); perm[p0] = t0;
  const int p1 = atomicAdd(&cur[e1], 1); perm[p1] = t1;
  if (tid == 0){
    float av = 0.f;
#pragma unroll
    for (int e = 0; e < 8; e++) av += (float)cnt[e] * psums[e];
    aux[0] += 8.f * av * (1.f / ((float)T_ * (float)T_));
  }
}

// ======================================================================
// MFMA GEMM, fp16x2 split (NPROD=3, fp32-grade) or single f16-hi (NPROD=1).
// LDS layout = fragment-native: [sub16][64 lanes][8 f16], lidx ^= (sub&7).
// EPI: 0=bias+store 1=bias+acc 2=bias+gelu+store(MoE hid) 3=moe scaled acc 4=store
// SWZROWS>0: 1D grid, XCD-chunked swizzle, rowTile = lb % SWZROWS.
// ANORM: fuse rmsnorm on A rows (pre-pass sumsq over L2-hot A + scale*nw[k]).
// ======================================================================
template<int BM, int BN, int NPROD, int EPI, bool MOE, bool APERM, int SWZROWS, bool ANORM>
__global__ __launch_bounds__(256) void k_mgemm(
    const float* __restrict__ A, const float* __restrict__ Bm,
    const float* __restrict__ bias, float* __restrict__ C,
    int M, int N, int K,
    const int* __restrict__ seg, const int* __restrict__ perm,
    const float* __restrict__ topw, const float* __restrict__ nw){
  constexpr int FM = BM / 32, FN = BN / 32;
  const int tid = threadIdx.x;
  int rowTile, colTile;
  if (SWZROWS > 0){
    const int nwg = gridDim.x;
    const int bid = blockIdx.x;
    const int lb = (bid & 7) * (nwg >> 3) + (bid >> 3);   // XCD-chunked (nwg%8==0)
    rowTile = lb % SWZROWS;
    colTile = lb / SWZROWS;
  } else {
    colTile = blockIdx.x; rowTile = blockIdx.y;
  }
  int e = 0, s0 = 0, cnt = M;
  if (MOE){ e = blockIdx.z; s0 = seg[e]; cnt = seg[e + 1] - s0; }
  const int row0 = rowTile * BM, col0 = colTile * BN;
  if (MOE && row0 >= cnt) return;
  const float* Bp = Bm + (size_t)e * K * N;
  const float* bp = bias + (size_t)e * N;

  __shared__ __align__(16) _Float16 Ah[BM * 32];
  __shared__ __align__(16) _Float16 Al[NPROD == 3 ? BM * 32 : 8];
  __shared__ __align__(16) _Float16 Bh[BN * 32];
  __shared__ __align__(16) _Float16 Bl[NPROD == 3 ? BN * 32 : 8];

  // A loader
  const int am = (BM == 64) ? (tid >> 2) : (tid >> 1);
  const int agrow = row0 + am;
  const bool aval = agrow < cnt;
  const float* Arow = nullptr;
  if (aval){
    int ridx = APERM ? perm[s0 + agrow] : (MOE ? s0 + agrow : agrow);
    Arow = A + (size_t)ridx * K;
  }
  const int asub = am >> 4;
  // B loader
  const int cb = (BN == 128) ? ((tid & 31) << 2) : ((tid & 15) << 2);
  const int p0 = (BN == 128) ? (tid >> 5) : (tid >> 4);
  constexpr int NBI = (BN == 128) ? 2 : 1;

  const int lane = tid & 63, w = tid >> 6;
  const int wm0 = (w >> 1) * (BM / 2), wn0 = (w & 1) * (BN / 2);

  // ---- ANORM pre-pass: rmsnorm scale for this A row ----
  float ascale = 1.f;
  if (ANORM){
    float ss = 0.f;
    if (BM == 64){
      const int kg = tid & 3;
      for (int k0 = 0; k0 < K; k0 += 32){
        const float4 a0 = *reinterpret_cast<const float4*>(Arow + k0 + (kg << 3));
        const float4 a1 = *reinterpret_cast<const float4*>(Arow + k0 + (kg << 3) + 4);
        ss += a0.x*a0.x + a0.y*a0.y + a0.z*a0.z + a0.w*a0.w
            + a1.x*a1.x + a1.y*a1.y + a1.z*a1.z + a1.w*a1.w;
      }
      ss += __shfl_xor(ss, 1);
      ss += __shfl_xor(ss, 2);
    } else {
      const int kgb = (tid & 1) << 1;
      for (int k0 = 0; k0 < K; k0 += 32){
#pragma unroll
        for (int kq = 0; kq < 2; kq++){
          const int kg = kgb + kq;
          const float4 a0 = *reinterpret_cast<const float4*>(Arow + k0 + (kg << 3));
          const float4 a1 = *reinterpret_cast<const float4*>(Arow + k0 + (kg << 3) + 4);
          ss += a0.x*a0.x + a0.y*a0.y + a0.z*a0.z + a0.w*a0.w
              + a1.x*a1.x + a1.y*a1.y + a1.z*a1.z + a1.w*a1.w;
        }
      }
      ss += __shfl_xor(ss, 1);
    }
    ascale = rsqrtf(ss * (1.f / (float)K) + 1e-6f);
  }

  f32x4_t acc_hh[FM][FN];
  f32x4_t acc_mx[NPROD == 3 ? FM : 1][NPROD == 3 ? FN : 1];
#pragma unroll
  for (int i = 0; i < FM; i++)
#pragma unroll
    for (int j = 0; j < FN; j++){
      acc_hh[i][j] = (f32x4_t){0.f, 0.f, 0.f, 0.f};
      if (NPROD == 3) acc_mx[i][j] = (f32x4_t){0.f, 0.f, 0.f, 0.f};
    }

  for (int k0 = 0; k0 < K; k0 += 32){
    // ---- stage A ----
    if (BM == 64){
      const int kg = tid & 3;
      float4 av0 = make_float4(0,0,0,0), av1 = make_float4(0,0,0,0);
      if (aval){
        av0 = *reinterpret_cast<const float4*>(Arow + k0 + (kg << 3));
        av1 = *reinterpret_cast<const float4*>(Arow + k0 + (kg << 3) + 4);
      }
      float a8[8] = {av0.x, av0.y, av0.z, av0.w, av1.x, av1.y, av1.z, av1.w};
      if (ANORM){
        const float4 w0 = *reinterpret_cast<const float4*>(nw + k0 + (kg << 3));
        const float4 w1 = *reinterpret_cast<const float4*>(nw + k0 + (kg << 3) + 4);
        const float wn8[8] = {w0.x, w0.y, w0.z, w0.w, w1.x, w1.y, w1.z, w1.w};
#pragma unroll
        for (int u = 0; u < 8; u++) a8[u] *= ascale * wn8[u];
      }
      half8_t hi, lo;
#pragma unroll
      for (int u = 0; u < 8; u++){
        hi[u] = (_Float16)a8[u];
        if (NPROD == 3) lo[u] = (_Float16)((a8[u] - (float)hi[u]) * 2048.f);
      }
      const int lidx = (am & 15) + (kg << 4);
      const int base = asub * 512 + ((lidx ^ (asub & 7)) << 3);
      *reinterpret_cast<half8_t*>(&Ah[base]) = hi;
      if (NPROD == 3) *reinterpret_cast<half8_t*>(&Al[base]) = lo;
    } else {
      const int kgb = (tid & 1) << 1;
#pragma unroll
      for (int kq = 0; kq < 2; kq++){
        const int kg = kgb + kq;
        float4 av0 = make_float4(0,0,0,0), av1 = make_float4(0,0,0,0);
        if (aval){
          av0 = *reinterpret_cast<const float4*>(Arow + k0 + (kg << 3));
          av1 = *reinterpret_cast<const float4*>(Arow + k0 + (kg << 3) + 4);
        }
        float a8[8] = {av0.x, av0.y, av0.z, av0.w, av1.x, av1.y, av1.z, av1.w};
        if (ANORM){
          const float4 w0 = *reinterpret_cast<const float4*>(nw + k0 + (kg << 3));
          const float4 w1 = *reinterpret_cast<const float4*>(nw + k0 + (kg << 3) + 4);
          const float wn8[8] = {w0.x, w0.y, w0.z, w0.w, w1.x, w1.y, w1.z, w1.w};
#pragma unroll
          for (int u = 0; u < 8; u++) a8[u] *= ascale * wn8[u];
        }
        half8_t hi;
#pragma unroll
        for (int u = 0; u < 8; u++) hi[u] = (_Float16)a8[u];
        const int lidx = (am & 15) + (kg << 4);
        *reinterpret_cast<half8_t*>(&Ah[asub * 512 + ((lidx ^ (asub & 7)) << 3)]) = hi;
      }
    }
    // ---- stage B ----
#pragma unroll
    for (int it = 0; it < NBI; it++){
      const int kk = ((BN == 128) ? (p0 + (it << 3)) : p0) << 1;
      const int kg = kk >> 3, e2 = kk & 7;
      const float4 b0 = *reinterpret_cast<const float4*>(Bp + (size_t)(k0 + kk) * N + col0 + cb);
      const float4 b1 = *reinterpret_cast<const float4*>(Bp + (size_t)(k0 + kk + 1) * N + col0 + cb);
      const float b0a[4] = {b0.x, b0.y, b0.z, b0.w};
      const float b1a[4] = {b1.x, b1.y, b1.z, b1.w};
#pragma unroll
      for (int j = 0; j < 4; j++){
        const int c = cb + j, sub = c >> 4;
        const int lidx = (c & 15) + (kg << 4);
        const int base = sub * 512 + ((lidx ^ (sub & 7)) << 3) + e2;
        _Float16 h0 = (_Float16)b0a[j], h1 = (_Float16)b1a[j];
        *reinterpret_cast<half2_t*>(&Bh[base]) = (half2_t){h0, h1};
        if (NPROD == 3){
          _Float16 l0 = (_Float16)((b0a[j] - (float)h0) * 2048.f);
          _Float16 l1 = (_Float16)((b1a[j] - (float)h1) * 2048.f);
          *reinterpret_cast<half2_t*>(&Bl[base]) = (half2_t){l0, l1};
        }
      }
    }
    __syncthreads();
    // ---- fragments + MFMA ----
    half8_t fAh[FM], fBh[FN];
    half8_t fAl[NPROD == 3 ? FM : 1], fBl[NPROD == 3 ? FN : 1];
#pragma unroll
    for (int fm = 0; fm < FM; fm++){
      const int s = (wm0 >> 4) + fm;
      const int ofs = s * 512 + ((lane ^ (s & 7)) << 3);
      fAh[fm] = *reinterpret_cast<const half8_t*>(&Ah[ofs]);
      if (NPROD == 3) fAl[fm] = *reinterpret_cast<const half8_t*>(&Al[ofs]);
    }
#pragma unroll
    for (int fn = 0; fn < FN; fn++){
      const int s = (wn0 >> 4) + fn;
      const int ofs = s * 512 + ((lane ^ (s & 7)) << 3);
      fBh[fn] = *reinterpret_cast<const half8_t*>(&Bh[ofs]);
      if (NPROD == 3) fBl[fn] = *reinterpret_cast<const half8_t*>(&Bl[ofs]);
    }
#pragma unroll
    for (int fm = 0; fm < FM; fm++)
#pragma unroll
      for (int fn = 0; fn < FN; fn++){
        acc_hh[fm][fn] = __builtin_amdgcn_mfma_f32_16x16x32_f16(
            fAh[fm], fBh[fn], acc_hh[fm][fn], 0, 0, 0);
        if (NPROD == 3){
          acc_mx[fm][fn] = __builtin_amdgcn_mfma_f32_16x16x32_f16(
              fAh[fm], fBl[fn], acc_mx[fm][fn], 0, 0, 0);
          acc_mx[fm][fn] = __builtin_amdgcn_mfma_f32_16x16x32_f16(
              fAl[fm], fBh[fn], acc_mx[fm][fn], 0, 0, 0);
        }
      }
    __syncthreads();
  }

  // ---- epilogue ----
  const int lr = lane & 15, kg4 = lane >> 4;
#pragma unroll
  for (int fm = 0; fm < FM; fm++){
#pragma unroll
    for (int reg = 0; reg < 4; reg++){
      const int grow = row0 + wm0 + fm * 16 + (kg4 << 2) + reg;
      if (grow >= cnt) continue;
      int trow = 0; float tw = 0.f;
      if (EPI == 3){ trow = perm[s0 + grow]; tw = topw[trow]; }
#pragma unroll
      for (int fn = 0; fn < FN; fn++){
        const int col = col0 + wn0 + fn * 16 + lr;
        float v = acc_hh[fm][fn][reg];
        if (NPROD == 3) v += acc_mx[fm][fn][reg] * (1.f / 2048.f);
        if (EPI == 0){
          C[(size_t)grow * N + col] = v + bp[col];
        } else if (EPI == 1){
          C[(size_t)grow * N + col] += v + bp[col];
        } else if (EPI == 2){
          C[(size_t)(s0 + grow) * N + col] = gelu_f(v + bp[col]);
        } else if (EPI == 3){
          C[(size_t)trow * N + col] += tw * (v + bp[col]);
        } else {
          C[(size_t)grow * N + col] = v;
        }
      }
    }
  }
}

// ======================================================================
// causal attention v5: MFMA flash + split-K + prefetch.
// Work units: qt<8 -> single block (direct write). qt>=8 -> two blocks:
//   slot0 = key-tiles 0..7 (no mask), slot1 = key-tiles 8..qt (diag mask);
//   both emit unnormalized partials (O, m, l); k_attn_comb merges.
// Grid = 384, longest chunks dispatched first.
// Prefetch: next tile's K/V global->regs issued right after LDS writes.
// ======================================================================
__global__ __launch_bounds__(256) void k_attn5(const float* __restrict__ qkv,
                                               float* __restrict__ o,
                                               float* __restrict__ attp,
                                               float* __restrict__ attml){
  __shared__ __align__(16) _Float16 Khi[4096], Klo[4096], Vhi[4096], Vlo[4096];
  __shared__ __align__(16) float pbuf[4][16 * 68];
  const int tid = threadIdx.x, w = tid >> 6, lane = tid & 63;
  const int lr = lane & 15, g = lane >> 4;
  const int bid = blockIdx.x;
  int bh, qt, kt0, kt1, mode;          // mode 0=direct, 1=partial slot0, 2=partial slot1
  if (bid < 128){        bh = bid >> 3;            qt = 8 + (bid & 7);  kt0 = 0; kt1 = 7;  mode = 1; }
  else if (bid < 256){   const int j = bid - 128;  bh = j >> 3; qt = 7 - (j & 7);  kt0 = 0; kt1 = qt; mode = 0; }
  else {                 const int j = bid - 256;  bh = j >> 3; qt = 15 - (j & 7); kt0 = 8; kt1 = qt; mode = 2; }
  const int b = bh >> 3, h = bh & 7;
  const size_t bbase = (size_t)(b << 10) * D3_;
  const int hoff = h * 64;
  const int qg = (qt << 6) + (w << 4) + lr;       // this lane's query

  // ---- Q fragments (B-operand), scale 1/8 folded ----
  half8_t qhi[2], qlo[2];
#pragma unroll
  for (int ks = 0; ks < 2; ks++){
    const float* qp = qkv + bbase + (size_t)qg * D3_ + hoff + ks * 32 + g * 8;
    const float4 f0 = *reinterpret_cast<const float4*>(qp);
    const float4 f1 = *reinterpret_cast<const float4*>(qp + 4);
    const float qa[8] = {f0.x, f0.y, f0.z, f0.w, f1.x, f1.y, f1.z, f1.w};
#pragma unroll
    for (int e = 0; e < 8; e++){
      const float v = qa[e] * 0.125f;
      const _Float16 hi = (_Float16)v;
      qhi[ks][e] = hi;
      qlo[ks][e] = (_Float16)((v - (float)hi) * 2048.f);
    }
  }

  float m = -1e30f, l = 0.f;
  f32x4_t oacc[4];
#pragma unroll
  for (int s = 0; s < 4; s++) oacc[s] = (f32x4_t){0.f, 0.f, 0.f, 0.f};

  const int kK = tid >> 2, quad = tid & 3;        // K staging: key row, d-quarter
  const int kp = tid >> 3, oct = tid & 7;         // V staging: key pair, d-octet

  float ka[16], va[8], vb[8];                     // prefetch registers
  auto loadregs = [&](int kt){
    const int j0 = kt << 6;
    const float* kr = qkv + bbase + (size_t)(j0 + kK) * D3_ + 512 + hoff + quad * 16;
    const float4 f0 = *reinterpret_cast<const float4*>(kr);
    const float4 f1 = *reinterpret_cast<const float4*>(kr + 4);
    const float4 f2 = *reinterpret_cast<const float4*>(kr + 8);
    const float4 f3 = *reinterpret_cast<const float4*>(kr + 12);
    ka[0]=f0.x; ka[1]=f0.y; ka[2]=f0.z; ka[3]=f0.w;
    ka[4]=f1.x; ka[5]=f1.y; ka[6]=f1.z; ka[7]=f1.w;
    ka[8]=f2.x; ka[9]=f2.y; ka[10]=f2.z; ka[11]=f2.w;
    ka[12]=f3.x; ka[13]=f3.y; ka[14]=f3.z; ka[15]=f3.w;
    const int k0v = kp << 1;
    const float* vr = qkv + bbase + (size_t)(j0 + k0v) * D3_ + 1024 + hoff + oct * 8;
    const float4 a0 = *reinterpret_cast<const float4*>(vr);
    const float4 a1 = *reinterpret_cast<const float4*>(vr + 4);
    const float4 b0 = *reinterpret_cast<const float4*>(vr + D3_);
    const float4 b1 = *reinterpret_cast<const float4*>(vr + D3_ + 4);
    va[0]=a0.x; va[1]=a0.y; va[2]=a0.z; va[3]=a0.w;
    va[4]=a1.x; va[5]=a1.y; va[6]=a1.z; va[7]=a1.w;
    vb[0]=b0.x; vb[1]=b0.y; vb[2]=b0.z; vb[3]=b0.w;
    vb[4]=b1.x; vb[5]=b1.y; vb[6]=b1.z; vb[7]=b1.w;
  };
  auto writelds = [&](){
    const int ksd = quad >> 1;
#pragma unroll
    for (int ch = 0; ch < 2; ch++){
      const int kgd = ((quad << 1) + ch) & 3;
      const int base = ksd * 2048 + (kK >> 4) * 512 + (((kK & 15) + (kgd << 4)) << 3);
      half8_t hi, lo;
#pragma unroll
      for (int e = 0; e < 8; e++){
        const float v = ka[ch * 8 + e];
        const _Float16 hv = (_Float16)v;
        hi[e] = hv;
        lo[e] = (_Float16)((v - (float)hv) * 2048.f);
      }
      *reinterpret_cast<half8_t*>(&Khi[base]) = hi;
      *reinterpret_cast<half8_t*>(&Klo[base]) = lo;
    }
    const int ksk = kp >> 4, kgk = (kp >> 2) & 3, e0 = (kp & 3) << 1;
#pragma unroll
    for (int j = 0; j < 8; j++){
      const int d = oct * 8 + j;
      const int lidx = (d & 15) + (kgk << 4);
      const int sw = lidx ^ kgk ^ (ksk << 2);
      const int fa = ksk * 2048 + (d >> 4) * 512 + (sw << 3) + e0;
      const _Float16 h0 = (_Float16)va[j], h1 = (_Float16)vb[j];
      *reinterpret_cast<half2_t*>(&Vhi[fa]) = (half2_t){h0, h1};
      const _Float16 l0 = (_Float16)((va[j] - (float)h0) * 2048.f);
      const _Float16 l1 = (_Float16)((vb[j] - (float)h1) * 2048.f);
      *reinterpret_cast<half2_t*>(&Vlo[fa]) = (half2_t){l0, l1};
    }
  };

  loadregs(kt0);
  for (int kt = kt0; kt <= kt1; kt++){
    const int j0 = kt << 6;
    __syncthreads();                  // prior-tile LDS reads done
    writelds();
    if (kt < kt1) loadregs(kt + 1);   // prefetch under compute
    __syncthreads();

    // ---- QK^T: D[key][q], 3-product split ----
    f32x4_t dfr[4];
#pragma unroll
    for (int s = 0; s < 4; s++){
      f32x4_t acc = (f32x4_t){0.f, 0.f, 0.f, 0.f};
      f32x4_t mix = (f32x4_t){0.f, 0.f, 0.f, 0.f};
#pragma unroll
      for (int ks = 0; ks < 2; ks++){
        const int base = ks * 2048 + s * 512 + lane * 8;
        const half8_t khi = *reinterpret_cast<const half8_t*>(&Khi[base]);
        const half8_t klo = *reinterpret_cast<const half8_t*>(&Klo[base]);
        acc = __builtin_amdgcn_mfma_f32_16x16x32_f16(khi, qhi[ks], acc, 0, 0, 0);
        mix = __builtin_amdgcn_mfma_f32_16x16x32_f16(khi, qlo[ks], mix, 0, 0, 0);
        mix = __builtin_amdgcn_mfma_f32_16x16x32_f16(klo, qhi[ks], mix, 0, 0, 0);
      }
#pragma unroll
      for (int r = 0; r < 4; r++) dfr[s][r] = acc[r] + mix[r] * (1.f / 2048.f);
    }
    // ---- causal mask (diagonal tile only) ----
    if (kt == qt){
#pragma unroll
      for (int s = 0; s < 4; s++)
#pragma unroll
        for (int r = 0; r < 4; r++){
          const int keyg = j0 + (g << 2) + r + (s << 4);
          if (keyg > qg) dfr[s][r] = -1e30f;
        }
    }
    // ---- online softmax ----
    float mloc = dfr[0][0];
#pragma unroll
    for (int s = 0; s < 4; s++)
#pragma unroll
      for (int r = 0; r < 4; r++) mloc = fmaxf(mloc, dfr[s][r]);
    mloc = fmaxf(mloc, __shfl_xor(mloc, 16));
    mloc = fmaxf(mloc, __shfl_xor(mloc, 32));
    const float mn = fmaxf(m, mloc);
    const float cr = __expf(m - mn);
    float psum = 0.f;
#pragma unroll
    for (int s = 0; s < 4; s++)
#pragma unroll
      for (int r = 0; r < 4; r++){
        const float p = __expf(dfr[s][r] - mn);
        psum += p;
        pbuf[w][lr * 68 + (s << 4) + (g << 2) + r] = p;
      }
    psum += __shfl_xor(psum, 16);
    psum += __shfl_xor(psum, 32);
    l = l * cr + psum;
    m = mn;
#pragma unroll
    for (int s = 0; s < 4; s++)
#pragma unroll
      for (int r = 0; r < 4; r++) oacc[s][r] *= cr;

    // ---- P -> B-operand fragments ----
    half8_t phi[2], plo[2];
#pragma unroll
    for (int ks = 0; ks < 2; ks++){
      const float* pp = &pbuf[w][lr * 68 + ks * 32 + g * 8];
      const float4 p0 = *reinterpret_cast<const float4*>(pp);
      const float4 p1 = *reinterpret_cast<const float4*>(pp + 4);
      const float pa[8] = {p0.x,p0.y,p0.z,p0.w, p1.x,p1.y,p1.z,p1.w};
#pragma unroll
      for (int e = 0; e < 8; e++){
        const _Float16 hv = (_Float16)pa[e];
        phi[ks][e] = hv;
        plo[ks][e] = (_Float16)((pa[e] - (float)hv) * 2048.f);
      }
    }
    // ---- PV: O^T[d][q] += V^T x P, 3-product split ----
#pragma unroll
    for (int s = 0; s < 4; s++){
      f32x4_t mix = (f32x4_t){0.f, 0.f, 0.f, 0.f};
#pragma unroll
      for (int ks = 0; ks < 2; ks++){
        const int sw = lane ^ g ^ (ks << 2);
        const int base = ks * 2048 + s * 512 + sw * 8;
        const half8_t vhi = *reinterpret_cast<const half8_t*>(&Vhi[base]);
        const half8_t vlo = *reinterpret_cast<const half8_t*>(&Vlo[base]);
        oacc[s] = __builtin_amdgcn_mfma_f32_16x16x32_f16(vhi, phi[ks], oacc[s], 0, 0, 0);
        mix = __builtin_amdgcn_mfma_f32_16x16x32_f16(vhi, plo[ks], mix, 0, 0, 0);
        mix = __builtin_amdgcn_mfma_f32_16x16x32_f16(vlo, phi[ks], mix, 0, 0, 0);
      }
#pragma unroll
      for (int r = 0; r < 4; r++) oacc[s][r] += mix[r] * (1.f / 2048.f);
    }
  }

  // ---- epilogue ----
  if (mode == 0){
    const float linv = 1.f / l;
    float* orow = o + (size_t)((b << 10) + qg) * D_ + hoff;
#pragma unroll
    for (int s = 0; s < 4; s++)
#pragma unroll
      for (int r = 0; r < 4; r++){
        const int d = (g << 2) + r + (s << 4);
        orow[d] = oacc[s][r] * linv;
      }
  } else {
    const int pidx = (((bh << 3) + (qt - 8)) << 1) + (mode - 1);
    float* pO = attp + (size_t)pidx * 4096;
    const int qloc = (w << 4) + lr;
#pragma unroll
    for (int s = 0; s < 4; s++)
#pragma unroll
      for (int r = 0; r < 4; r++){
        const int d = (g << 2) + r + (s << 4);
        pO[qloc * 64 + d] = oacc[s][r];
      }
    if (g == 0){
      attml[pidx * 128 + qloc]      = m;
      attml[pidx * 128 + 64 + qloc] = l;
    }
  }
}

// ---------- attention combine: merge the two split-K halves ----------
__global__ __launch_bounds__(256) void k_attn_comb(const float* __restrict__ attp,
                                                   const float* __restrict__ attml,
                                                   float* __restrict__ o){
  const int bid = blockIdx.x;                   // 0..127 = bh*8 + (qt-8)
  const int bh = bid >> 3, i = bid & 7, qt = 8 + i;
  const int b = bh >> 3, h = bh & 7;
  const int pidx0 = ((bh << 3) + i) << 1;
  const float* pA = attp + (size_t)pidx0 * 4096;
  const float* pB = pA + 4096;
  const float* mlA = attml + pidx0 * 128;
  const float* mlB = mlA + 128;
  const int tid = threadIdx.x;
  const int q = tid >> 2, dg = (tid & 3) << 4;
  const float mA = mlA[q], lA = mlA[64 + q];
  const float mB = mlB[q], lB = mlB[64 + q];
  const float M = fmaxf(mA, mB);
  const float cA = __expf(mA - M), cB = __expf(mB - M);
  const float linv = 1.f / (lA * cA + lB * cB);
  float* orow = o + (size_t)((b << 10) + (qt << 6) + q) * D_ + h * 64;
#pragma unroll
  for (int j = 0; j < 4; j++){
    const int d = dg + (j << 2);
    const float4 a = *reinterpret_cast<const float4*>(pA + q * 64 + d);
    const float4 bb = *reinterpret_cast<const float4*>(pB + q * 64 + d);
    *reinterpret_cast<float4*>(orow + d) = make_float4(
        (a.x * cA + bb.x * cB) * linv, (a.y * cA + bb.y * cB) * linv,
        (a.z * cA + bb.z * cB) * linv, (a.w * cA + bb.w * cB) * linv);
  }
}

// ======================= host launcher =======================
extern "C" void kernel_launch(void* const* d_in, const int* in_sizes, int n_in,
                              void* d_out, int out_size, void* d_ws, size_t ws_size,
                              hipStream_t stream){
  const int*   ids  = (const int*)  d_in[0];
  const float* tok  = (const float*)d_in[1];
  const float* pos  = (const float*)d_in[2];
  const float* Wqkv = (const float*)d_in[3];
  const float* bqkv = (const float*)d_in[4];
  const float* Wo   = (const float*)d_in[5];
  const float* bo   = (const float*)d_in[6];
  const float* rW   = (const float*)d_in[7];
  const float* rb   = (const float*)d_in[8];
  const float* eW1  = (const float*)d_in[9];
  const float* eb1  = (const float*)d_in[10];
  const float* eW2  = (const float*)d_in[11];
  const float* eb2  = (const float*)d_in[12];
  const float* n1w  = (const float*)d_in[13];
  const float* n2w  = (const float*)d_in[14];
  const float* noww = (const float*)d_in[15];
  const float* lmW  = (const float*)d_in[16];

  float* out    = (float*)d_out;
  float* logits = out;                             // [T,V]
  float* aux    = out + (size_t)T_ * V_;           // [1]
  float* rlog   = aux + 1;                         // [L,T,E]

  float* ws = (float*)d_ws;
  size_t off = 0;
  float* x     = ws + off; off += (size_t)T_ * D_;
  float* h     = ws + off; off += (size_t)T_ * D_;
  float* qkv   = ws + off; off += (size_t)T_ * D3_;
  float* attno = ws + off; off += (size_t)T_ * D_;
  float* hid   = ws + off; off += (size_t)T_ * FF_;
  float* topw  = ws + off; off += T_;
  int* topi    = (int*)(ws + off); off += T_;
  int* perm    = (int*)(ws + off); off += T_;
  int* seg     = (int*)(ws + off); off += (E_ + 1);
  float* attp  = ws + off; off += 16 * 8 * 2 * 4096;   // split-K partial O
  float* attml = ws + off; off += 16 * 8 * 2 * 128;    // split-K partial m,l

  hipMemsetAsync(aux, 0, sizeof(float), stream);
  k_embed<<<T_, 256, 0, stream>>>(ids, tok, pos, x);

  for (int l = 0; l < L_; l++){
    // --- attention block (rmsnorm1 fused into qkv GEMM) ---
    k_mgemm<64, 128, 3, 0, false, false, 0, true><<<dim3(D3_ / 128, T_ / 64), 256, 0, stream>>>(
        x, Wqkv + (size_t)l * D_ * D3_, bqkv + (size_t)l * D3_, qkv,
        T_, D3_, D_, seg, perm, topw, n1w + (size_t)l * D_);
    k_attn5<<<384, 256, 0, stream>>>(qkv, attno, attp, attml);
    k_attn_comb<<<128, 256, 0, stream>>>(attp, attml, attno);
    k_mgemm<64, 64, 3, 1, false, false, 0, false><<<dim3(D_ / 64, T_ / 64), 256, 0, stream>>>(
        attno, Wo + (size_t)l * D_ * D_, bo + (size_t)l * D_, x,
        T_, D_, D_, seg, perm, topw, nullptr);
    // --- MoE block ---
    k_norm_router<<<T_, 64, 0, stream>>>(x, n2w + (size_t)l * D_,
        rW + (size_t)l * D_ * E_, rb + (size_t)l * E_,
        h, rlog + (size_t)l * T_ * E_, topw, topi);
    k_route_scan2<<<1, 1024, 0, stream>>>(topi, rlog + (size_t)l * T_ * E_, seg, perm, aux);
    k_mgemm<64, 128, 3, 2, true, true, 0, false><<<dim3(FF_ / 128, T_ / 64, E_), 256, 0, stream>>>(
        h, eW1 + (size_t)l * E_ * D_ * FF_, eb1 + (size_t)l * E_ * FF_, hid,
        T_, FF_, D_, seg, perm, topw, nullptr);
    k_mgemm<64, 64, 3, 3, true, false, 0, false><<<dim3(D_ / 64, T_ / 64, E_), 256, 0, stream>>>(
        hid, eW2 + (size_t)l * E_ * FF_ * D_, eb2 + (size_t)l * E_ * D_, x,
        T_, D_, FF_, seg, perm, topw, nullptr);
  }

  // --- LM head (final rmsnorm fused; f16-hi; XCD-chunked 1D grid) ---
  k_mgemm<128, 128, 1, 4, false, false, 16, true><<<(T_ / 128) * (V_ / 128), 256, 0, stream>>>(
      x, lmW, nullptr, logits, T_, V_, D_, seg, perm, topw, noww);
}